// Round 1
// baseline (166.566 us; speedup 1.0000x reference)
//
#include <hip/hip_runtime.h>

// Problem constants (from reference): B=32, N=2048, FE=32, T=12, OUT=3
#define FE_ 32
#define T_  12
#define M_  (32 * 2048)

// One thread per sequence m. x[m] is a contiguous (FE=32, T=12) fp32 block
// (1536 B). Gate pre-activations gates_x[t][g] = sum_f x[m][f][t]*w_ih[g][f]
// accumulate in registers while streaming f; then the 12-step scalar GRU
// recurrence + 3-wide output GEMV, all in registers.
__global__ __launch_bounds__(256) void gru_seq_kernel(
    const float* __restrict__ x,
    const float* __restrict__ w_ih,   // (3, 32)
    const float* __restrict__ w_hh,   // (3, 1)
    const float* __restrict__ b_ih,   // (3,)
    const float* __restrict__ b_hh,   // (3,)
    const float* __restrict__ lin_w,  // (3, 12)
    const float* __restrict__ lin_b,  // (3,)
    float* __restrict__ out)          // (M, 3)
{
    const int m = blockIdx.x * blockDim.x + threadIdx.x;
    if (m >= M_) return;

    // gate accumulators, init with b_ih (broadcast over t)
    float acc0[T_], acc1[T_], acc2[T_];
    const float bi0 = b_ih[0], bi1 = b_ih[1], bi2 = b_ih[2];
#pragma unroll
    for (int t = 0; t < T_; ++t) { acc0[t] = bi0; acc1[t] = bi1; acc2[t] = bi2; }

    // stream the thread's contiguous 1536B row: 3 float4 per f (12 t-values)
    const float4* __restrict__ xrow =
        (const float4*)(x + (size_t)m * (FE_ * T_));

#pragma unroll 4
    for (int f = 0; f < FE_; ++f) {
        const float4 a = xrow[f * 3 + 0];
        const float4 b = xrow[f * 3 + 1];
        const float4 c = xrow[f * 3 + 2];
        const float xv[T_] = { a.x, a.y, a.z, a.w,
                               b.x, b.y, b.z, b.w,
                               c.x, c.y, c.z, c.w };
        // wave-uniform weight loads -> scalarized / L1-broadcast
        const float w0 = w_ih[0 * FE_ + f];
        const float w1 = w_ih[1 * FE_ + f];
        const float w2 = w_ih[2 * FE_ + f];
#pragma unroll
        for (int t = 0; t < T_; ++t) {
            acc0[t] = fmaf(xv[t], w0, acc0[t]);
            acc1[t] = fmaf(xv[t], w1, acc1[t]);
            acc2[t] = fmaf(xv[t], w2, acc2[t]);
        }
    }

    const float wh0 = w_hh[0], wh1 = w_hh[1], wh2 = w_hh[2];
    const float bh0 = b_hh[0], bh1 = b_hh[1], bh2 = b_hh[2];
    float o0 = lin_b[0], o1 = lin_b[1], o2 = lin_b[2];

    float h = 0.0f;
#pragma unroll
    for (int t = 0; t < T_; ++t) {
        // r = sigmoid(gx0 + wh0*h + bh0); z = sigmoid(gx1 + wh1*h + bh1)
        const float r = 1.0f / (1.0f + __expf(-(acc0[t] + wh0 * h + bh0)));
        const float z = 1.0f / (1.0f + __expf(-(acc1[t] + wh1 * h + bh1)));
        // n = tanh(gx2 + r*(wh2*h + bh2));  tanh(y) = 1 - 2/(1+exp(2y))
        const float y = acc2[t] + r * (wh2 * h + bh2);
        const float n = 1.0f - 2.0f / (1.0f + __expf(2.0f * y));
        h = (1.0f - z) * n + z * h;
        const float ht = h > 0.0f ? h : 0.0f;  // relu
        o0 = fmaf(ht, lin_w[0 * T_ + t], o0);
        o1 = fmaf(ht, lin_w[1 * T_ + t], o1);
        o2 = fmaf(ht, lin_w[2 * T_ + t], o2);
    }

    float* __restrict__ po = out + (size_t)m * 3;
    po[0] = o0; po[1] = o1; po[2] = o2;
}

extern "C" void kernel_launch(void* const* d_in, const int* in_sizes, int n_in,
                              void* d_out, int out_size, void* d_ws, size_t ws_size,
                              hipStream_t stream) {
    (void)in_sizes; (void)n_in; (void)d_ws; (void)ws_size; (void)out_size;
    const float* x     = (const float*)d_in[0];
    const float* w_ih  = (const float*)d_in[1];
    const float* w_hh  = (const float*)d_in[2];
    const float* b_ih  = (const float*)d_in[3];
    const float* b_hh  = (const float*)d_in[4];
    const float* lin_w = (const float*)d_in[5];
    const float* lin_b = (const float*)d_in[6];
    float* out = (float*)d_out;

    const int block = 256;
    const int grid = (M_ + block - 1) / block;  // 256 blocks
    gru_seq_kernel<<<grid, block, 0, stream>>>(x, w_ih, w_hh, b_ih, b_hh,
                                               lin_w, lin_b, out);
}

// Round 2
// 159.075 us; speedup vs baseline: 1.0471x; 1.0471x over previous
//
#include <hip/hip_runtime.h>

// B=32, N=2048, FE=32, T=12, OUT=3
#define FE_ 32
#define T_  12
#define M_  (32 * 2048)
#define SEQ_PER_BLOCK 32
#define THREADS (SEQ_PER_BLOCK * T_)   // 384 = 6 waves
#define LDS_STRIDE 37                  // 36 gate floats + 1 pad (odd => conflict-free)

// Thread (s,t) computes the 3 gate pre-activations for (sequence m0+s, step t)
// with t as the fastest lane axis => near-coalesced x reads (t is the innermost
// axis of x). Gates round-trip through LDS; lanes 0..31 then run the 12-step
// recurrence + output GEMV for their sequence.
__global__ __launch_bounds__(THREADS) void gru_fused_kernel(
    const float* __restrict__ x,      // (M, FE, T)
    const float* __restrict__ w_ih,   // (3, FE)
    const float* __restrict__ w_hh,   // (3, 1)
    const float* __restrict__ b_ih,   // (3,)
    const float* __restrict__ b_hh,   // (3,)
    const float* __restrict__ lin_w,  // (3, T)
    const float* __restrict__ lin_b,  // (3,)
    float* __restrict__ out)          // (M, 3)
{
    __shared__ float gbuf[SEQ_PER_BLOCK * LDS_STRIDE];

    const int tid = threadIdx.x;
    const int s   = tid / T_;          // local sequence 0..31
    const int t   = tid - s * T_;      // time step 0..11
    const int m0  = blockIdx.x * SEQ_PER_BLOCK;

    // ---- phase 1: gate pre-activations gates[t][g] for sequence m0+s ----
    const float* __restrict__ xp = x + (size_t)(m0 + s) * (FE_ * T_) + t;
    float a0 = b_ih[0], a1 = b_ih[1], a2 = b_ih[2];
#pragma unroll
    for (int f = 0; f < FE_; ++f) {
        const float xv = xp[f * T_];               // lane-coalesced along t
        a0 = fmaf(xv, w_ih[0 * FE_ + f], a0);      // w_ih reads are wave-uniform
        a1 = fmaf(xv, w_ih[1 * FE_ + f], a1);
        a2 = fmaf(xv, w_ih[2 * FE_ + f], a2);
    }
    float* g = &gbuf[s * LDS_STRIDE + t * 3];
    g[0] = a0; g[1] = a1; g[2] = a2;
    __syncthreads();

    // ---- phase 2: recurrence + output head, one lane per sequence ----
    if (tid < SEQ_PER_BLOCK) {
        const float wh0 = w_hh[0], wh1 = w_hh[1], wh2 = w_hh[2];
        const float bh0 = b_hh[0], bh1 = b_hh[1], bh2 = b_hh[2];
        float o0 = lin_b[0], o1 = lin_b[1], o2 = lin_b[2];
        const float* __restrict__ gg = &gbuf[tid * LDS_STRIDE]; // stride 37: no bank conflicts
        float h = 0.0f;
#pragma unroll
        for (int tt = 0; tt < T_; ++tt) {
            const float r = 1.0f / (1.0f + __expf(-(gg[tt * 3 + 0] + wh0 * h + bh0)));
            const float z = 1.0f / (1.0f + __expf(-(gg[tt * 3 + 1] + wh1 * h + bh1)));
            const float y = gg[tt * 3 + 2] + r * (wh2 * h + bh2);
            const float n = 1.0f - 2.0f / (1.0f + __expf(2.0f * y));  // tanh(y)
            h = (1.0f - z) * n + z * h;
            const float ht = h > 0.0f ? h : 0.0f;                      // relu
            o0 = fmaf(ht, lin_w[0 * T_ + tt], o0);
            o1 = fmaf(ht, lin_w[1 * T_ + tt], o1);
            o2 = fmaf(ht, lin_w[2 * T_ + tt], o2);
        }
        float* __restrict__ po = out + (size_t)(m0 + tid) * 3;
        po[0] = o0; po[1] = o1; po[2] = o2;   // 32 lanes x 12 B contiguous
    }
}

extern "C" void kernel_launch(void* const* d_in, const int* in_sizes, int n_in,
                              void* d_out, int out_size, void* d_ws, size_t ws_size,
                              hipStream_t stream) {
    (void)in_sizes; (void)n_in; (void)d_ws; (void)ws_size; (void)out_size;
    const float* x     = (const float*)d_in[0];
    const float* w_ih  = (const float*)d_in[1];
    const float* w_hh  = (const float*)d_in[2];
    const float* b_ih  = (const float*)d_in[3];
    const float* b_hh  = (const float*)d_in[4];
    const float* lin_w = (const float*)d_in[5];
    const float* lin_b = (const float*)d_in[6];
    float* out = (float*)d_out;

    const int grid = M_ / SEQ_PER_BLOCK;   // 2048 blocks
    gru_fused_kernel<<<grid, THREADS, 0, stream>>>(x, w_ih, w_hh, b_ih, b_hh,
                                                   lin_w, lin_b, out);
}